// Round 1
// baseline (241.345 us; speedup 1.0000x reference)
//
#include <hip/hip_runtime.h>
#include <hip/hip_bf16.h>
#include <math.h>
#include <stdint.h>

// ScaleAdaptiveRouter on MI355X (gfx950) — Round 13
// T=16384, H=2048, E=64, K=2112, top-2.
//
// R12 (78us) diagnosis: MfmaUtil 12%, VALUBusy 26%, HBM 12%, Occupancy 20%
// -> no pipe saturated; TLP-starved at 8 waves/CU with a per-step
// block-wide barrier. Depth-3 glds prefetch already over-covers latency.
// R13: same verified mechanism (glds 4-slot multibuffer, raw
// "s_waitcnt vmcnt(N); s_barrier", XOR-granule A swizzle, bf16x3 6-term
// MFMA, verified epilogue) restructured to 512-thread / 8-wave blocks:
// wave = (mt 0/1) x (g 0..3), 16 tokens x 16 experts per wave
// -> 16 waves/CU (4/SIMD), 2x the co-resident work to fill barrier stalls.
// Set layout [A 4KB | B 12KB]: thread t stages chunks {t, t+512}
// (dsts t*16 / t*16+8192 are wave-linear per m104), uniform 2 glds/step
// -> uniform vmcnt(4) wait, 2 sets in flight across the barrier.
// ISSUE_SET hoisted to just after the barrier (slot (s+3)&3=(s-1)&3 was
// last read pre-barrier) for one extra compute-phase of latency slack.

#define H_DIM 2048
#define K_TOTAL 2112
#define E_DIM 64
#define SE_DIM 64
#define NSTEP 64                        // K32 steps over H
#define TPB 32                          // tokens per block
#define NBLOCKS (16384 / TPB)           // 512 -> 2 blocks/CU
#define STEP_BYTES (12 * 1024)          // 12 B-records of 1 KB per step
#define SET_BYTES (16 * 1024)           // A 4KB + B 12KB
#define WP_TOTAL (NSTEP * STEP_BYTES)   // 786432 B
#define MINS(v) ((v) < NSTEP ? (v) : (NSTEP - 1))

typedef float  f32x4 __attribute__((ext_vector_type(4)));
typedef short  s16x8 __attribute__((ext_vector_type(8)));
typedef unsigned int u32x4 __attribute__((ext_vector_type(4)));

typedef uint32_t __attribute__((address_space(1))) gu32_t;
typedef uint32_t __attribute__((address_space(3))) lu32_t;
__device__ __forceinline__ void gload_lds16(const void* g, void* l) {
    __builtin_amdgcn_global_load_lds((const gu32_t*)g, (lu32_t*)l, 16, 0, 0);
}

__device__ __forceinline__ unsigned short bf16_rne(float f) {
    uint32_t u = __float_as_uint(f);
    return (unsigned short)((u + 0x7FFFu + ((u >> 16) & 1u)) >> 16);
}
__device__ __forceinline__ float bf16_f32(unsigned short h) {
    return __uint_as_float(((uint32_t)h) << 16);
}
__device__ __forceinline__ uint32_t bits_of_bf2(__hip_bfloat162 h) {
    uint32_t u; __builtin_memcpy(&u, &h, 4); return u;
}

// ---- prep: split W into 3 bf16 planes laid out as MFMA B-fragments ----
// B-frag (16x16x32): lane l -> n = l&15, k = (l>>4)*8 + j. Record (s,nt,p):
// 64 lanes x 8 bf16 = 1 KB; record index = s*12 + nt*3 + p.  [R6-verified]
__global__ void prep_kernel(const float* __restrict__ W,
                            const float* __restrict__ se,
                            const int* __restrict__ sidx,
                            unsigned short* __restrict__ Wp,
                            float* __restrict__ tail) {
    if (blockIdx.x == 64) {
        int e = threadIdx.x;
        if (e < 64) {
            const float* emb = se + (*sidx) * SE_DIM;
            float t = 0.f;
            for (int j = 0; j < SE_DIM; ++j)
                t = fmaf(emb[j], W[(size_t)e * K_TOTAL + H_DIM + j], t);
            tail[e] = t;
        }
        return;
    }
    int item = blockIdx.x * 256 + threadIdx.x;   // (s, nt, lane)
    int lane = item & 63;
    int nt   = (item >> 6) & 3;
    int s    = item >> 8;
    int e     = nt * 16 + (lane & 15);
    int kbase = s * 32 + (lane >> 4) * 8;
    const float* wr = W + (size_t)e * K_TOTAL + kbase;
    unsigned short p0[8], p1[8], p2[8];
    #pragma unroll
    for (int j = 0; j < 8; ++j) {
        float v = wr[j];
        unsigned short a0 = bf16_rne(v);
        float r1 = v - bf16_f32(a0);
        unsigned short a1 = bf16_rne(r1);
        float r2 = r1 - bf16_f32(a1);
        p0[j] = a0; p1[j] = a1; p2[j] = bf16_rne(r2);
    }
    size_t rec = (size_t)s * 12 + nt * 3;
    unsigned short* d0 = Wp + (rec + 0) * 512 + lane * 8;
    unsigned short* d1 = Wp + (rec + 1) * 512 + lane * 8;
    unsigned short* d2 = Wp + (rec + 2) * 512 + lane * 8;
    #pragma unroll
    for (int j = 0; j < 8; ++j) { d0[j] = p0[j]; d1[j] = p1[j]; d2[j] = p2[j]; }
}

// split 8 consecutive-k floats into 3 bf16 A-fragment planes (packed pairs)
__device__ __forceinline__ void split3(const float4 fa, const float4 fb,
                                       s16x8& P0, s16x8& P1, s16x8& P2) {
    float f[8] = {fa.x, fa.y, fa.z, fa.w, fb.x, fb.y, fb.z, fb.w};
    uint32_t d0[4], d1[4], d2[4];
    #pragma unroll
    for (int p = 0; p < 4; ++p) {
        float v0 = f[2 * p], v1 = f[2 * p + 1];
        uint32_t u0 = bits_of_bf2(__float22bfloat162_rn(make_float2(v0, v1)));
        float r0 = v0 - __uint_as_float(u0 << 16);
        float r1 = v1 - __uint_as_float(u0 & 0xffff0000u);
        uint32_t u1 = bits_of_bf2(__float22bfloat162_rn(make_float2(r0, r1)));
        float s0 = r0 - __uint_as_float(u1 << 16);
        float s1 = r1 - __uint_as_float(u1 & 0xffff0000u);
        uint32_t u2 = bits_of_bf2(__float22bfloat162_rn(make_float2(s0, s1)));
        d0[p] = u0; d1[p] = u1; d2[p] = u2;
    }
    u32x4 q0 = {d0[0], d0[1], d0[2], d0[3]};
    u32x4 q1 = {d1[0], d1[1], d1[2], d1[3]};
    u32x4 q2 = {d2[0], d2[1], d2[2], d2[3]};
    __builtin_memcpy(&P0, &q0, 16);
    __builtin_memcpy(&P1, &q1, 16);
    __builtin_memcpy(&P2, &q2, 16);
}

__launch_bounds__(512, 4)
__global__ void router_kernel(const float* __restrict__ x,
                              const unsigned char* __restrict__ Wp,
                              const float* __restrict__ tail_g,
                              const float* __restrict__ noise,
                              float* __restrict__ out) {
    __shared__ __align__(16) unsigned char S[4][SET_BYTES];  // 64 KB slots
    __shared__ float4 cand[4][TPB];                          // 2 KB
    __shared__ float4 res[TPB];                              // 0.5 KB

    const int tid  = threadIdx.x;                    // 0..511
    const int lane = tid & 63;
    const int wave = __builtin_amdgcn_readfirstlane(tid >> 6);  // 0..7
    const int mt   = wave >> 2;          // token half (16 tokens)
    const int g    = wave & 3;           // expert group: experts g*16..g*16+15
    const int tok0 = blockIdx.x * TPB;
    const int row  = lane & 15;          // token within m-tile
    const int quad = lane >> 4;          // k-quad
    const int c    = row;                // expert col within 16-slice

    // ---- staging: thread t loads set chunks {t, t+512} (16 B each) ----
    // set = [A 4KB (chunks 0..255) | B 12KB (chunks 256..1023)]
    // A chunk a: stok=a>>3, spos=a&7, src chunk spos^(stok&7)  (XOR swizzle)
    //   dst = stok*128 + spos*16 = a*16  (wave-linear, m104-safe)
    const char* s1; size_t str1;
    if (tid < 256) {
        int st = tid >> 3, sp = tid & 7;
        s1 = (const char*)(x + (size_t)(tok0 + st) * H_DIM + ((sp ^ (st & 7)) << 2));
        str1 = 128;                       // 32 floats of k per step
    } else {
        s1 = (const char*)Wp + (size_t)(tid - 256) * 16;
        str1 = STEP_BYTES;
    }
    const char* s2 = (const char*)Wp + (size_t)(tid + 256) * 16;  // chunk t+512
    const int d1 = tid * 16;
    const int d2 = tid * 16 + 8192;

    // A fragment read offsets: token mt*16+row, chunks 2q,2q+1 (deswizzled)
    const int abase = (mt * 16 + row) * 128;
    const int aoff0 = abase + (((quad * 2)     ^ (row & 7)) << 4);
    const int aoff1 = abase + (((quad * 2 + 1) ^ (row & 7)) << 4);
    const int boff  = 4096 + g * 3072 + lane * 16;   // records g*3 + {0,1,2}

    f32x4 acc = {0.f, 0.f, 0.f, 0.f};

    #define ISSUE_SET(s_, d_) do {                                  \
        gload_lds16(s1 + (size_t)(s_) * str1,       &S[d_][d1]);    \
        gload_lds16(s2 + (size_t)(s_) * STEP_BYTES, &S[d_][d2]);    \
    } while (0)

    // ---- prologue: 3 sets in flight (6 glds/thread outstanding) ----
    ISSUE_SET(0, 0);
    ISSUE_SET(1, 1);
    ISSUE_SET(2, 2);

    for (int s = 0; s < NSTEP; ++s) {
        // drain only the oldest set (2 glds); 2 newer sets cross the barrier
        asm volatile("s_waitcnt vmcnt(4)\n\ts_barrier" ::: "memory");

        // issue set s+3 into slot (s+3)&3 = (s-1)&3: last read at step s-1,
        // and all waves passed that read before this barrier released.
        ISSUE_SET(MINS(s + 3), (s + 3) & 3);

        const unsigned char* sb = &S[s & 3][0];
        float4 a0 = *(const float4*)(sb + aoff0);
        float4 a1 = *(const float4*)(sb + aoff1);
        s16x8 A0, A1, A2;
        split3(a0, a1, A0, A1, A2);

        const unsigned char* bb = sb + boff;
        s16x8 B0 = *(const s16x8*)(bb);
        s16x8 B1 = *(const s16x8*)(bb + 1024);
        s16x8 B2 = *(const s16x8*)(bb + 2048);
        acc = __builtin_amdgcn_mfma_f32_16x16x32_bf16(A0, B0, acc, 0, 0, 0);
        acc = __builtin_amdgcn_mfma_f32_16x16x32_bf16(A0, B1, acc, 0, 0, 0);
        acc = __builtin_amdgcn_mfma_f32_16x16x32_bf16(A1, B0, acc, 0, 0, 0);
        acc = __builtin_amdgcn_mfma_f32_16x16x32_bf16(A0, B2, acc, 0, 0, 0);
        acc = __builtin_amdgcn_mfma_f32_16x16x32_bf16(A1, B1, acc, 0, 0, 0);
        acc = __builtin_amdgcn_mfma_f32_16x16x32_bf16(A2, B0, acc, 0, 0, 0);
    }
    #undef ISSUE_SET

    // ---- epilogue: tail + noise, top-2 over this wave's 16 experts ----
    // C/D: col = lane&15 -> expert g*16 + c; row = quad*4 + r -> token
    float tl = tail_g[g * 16 + c];
    #pragma unroll
    for (int r = 0; r < 4; ++r) {
        const int tlk = mt * 16 + quad * 4 + r;             // block-local token
        const float* nz = noise + (size_t)(tok0 + tlk) * E_DIM + g * 16;
        float v = acc[r] + tl + 0.1f * nz[c];
        float V1 = v, V2 = -3.4e38f;
        int   I1 = g * 16 + c, I2 = 0x7fffffff;
        // butterfly over the 16 lanes of this quad group (same token)
        #pragma unroll
        for (int m = 8; m; m >>= 1) {
            float o1 = __shfl_xor(V1, m, 64); int oi1 = __shfl_xor(I1, m, 64);
            float o2 = __shfl_xor(V2, m, 64); int oi2 = __shfl_xor(I2, m, 64);
            if (o1 > V1 || (o1 == V1 && oi1 < I1)) {
                float nv2; int ni2;
                if (V1 > o2 || (V1 == o2 && I1 < oi2)) { nv2 = V1; ni2 = I1; }
                else                                   { nv2 = o2; ni2 = oi2; }
                V1 = o1; I1 = oi1; V2 = nv2; I2 = ni2;
            } else {
                if (o1 > V2 || (o1 == V2 && oi1 < I2)) { V2 = o1; I2 = oi1; }
            }
        }
        if (c == r)
            cand[g][tlk] = make_float4(V1, __int_as_float(I1), V2, __int_as_float(I2));
    }
    __syncthreads();

    // ---- merge the four 16-expert groups per token (disjoint ascending
    //      index ranges: strict > keeps the lower index on exact ties) ----
    if (tid < TPB) {
        float4 q0 = cand[0][tid];
        float V1 = q0.x, V2 = q0.z;
        int   I1 = __float_as_int(q0.y), I2 = __float_as_int(q0.w);
        #pragma unroll
        for (int j = 1; j < 4; ++j) {
            float4 qj = cand[j][tid];
            float o1 = qj.x, o2 = qj.z;
            int  oi1 = __float_as_int(qj.y), oi2 = __float_as_int(qj.w);
            if (o1 > V1) {
                if (o2 > V1) { V2 = o2; I2 = oi2; }
                else         { V2 = V1; I2 = I1;  }
                V1 = o1; I1 = oi1;
            } else if (o1 > V2) {
                V2 = o1; I2 = oi1;
            }
        }
        float d   = expf(V2 - V1);                  // softmax denom cancels
        float inv = 1.0f / (1.0f + d);
        res[tid] = make_float4(inv, __int_as_float(I1), d * inv, __int_as_float(I2));
    }
    __syncthreads();

    // ---- composed coalesced store: 32 tokens x 64 experts = 512 float4 ----
    float4* outb = (float4*)out + (size_t)blockIdx.x * (TPB * E_DIM / 4);
    {
        int t = tid >> 4, cc = tid & 15;
        float4 rr = res[t];
        int ri1 = __float_as_int(rr.y), ri2 = __float_as_int(rr.w);
        int e = cc * 4;
        float4 o;
        o.x = (e + 0 == ri1) ? rr.x : (e + 0 == ri2) ? rr.z : 0.0f;
        o.y = (e + 1 == ri1) ? rr.x : (e + 1 == ri2) ? rr.z : 0.0f;
        o.z = (e + 2 == ri1) ? rr.x : (e + 2 == ri2) ? rr.z : 0.0f;
        o.w = (e + 3 == ri1) ? rr.x : (e + 3 == ri2) ? rr.z : 0.0f;
        outb[tid] = o;
    }
}

extern "C" void kernel_launch(void* const* d_in, const int* in_sizes, int n_in,
                              void* d_out, int out_size, void* d_ws, size_t ws_size,
                              hipStream_t stream) {
    const float* x     = (const float*)d_in[0];
    const float* se    = (const float*)d_in[1];
    const float* W     = (const float*)d_in[2];
    const float* noise = (const float*)d_in[3];
    const int*   sidx  = (const int*)d_in[4];
    float* out = (float*)d_out;

    unsigned short* Wp   = (unsigned short*)d_ws;                 // 786432 B
    float*          tail = (float*)((char*)d_ws + WP_TOTAL);      // 256 B

    hipLaunchKernelGGL(prep_kernel, dim3(65), dim3(256), 0, stream, W, se, sidx, Wp, tail);
    hipLaunchKernelGGL(router_kernel, dim3(NBLOCKS), dim3(512), 0, stream,
                       x, (const unsigned char*)Wp, tail, noise, out);
}